// Round 2
// baseline (330.012 us; speedup 1.0000x reference)
//
#include <hip/hip_runtime.h>

typedef _Float16 f16;
typedef _Float16 half8 __attribute__((ext_vector_type(8)));
typedef _Float16 half4 __attribute__((ext_vector_type(4)));
typedef float f32x4 __attribute__((ext_vector_type(4)));

#define B_SZ 512
#define NQ   128
#define CH   512
#define NH   8
#define DH   64
#define MTOK (B_SZ*NQ)   // 65536 tokens
#define KD   512

#define MFMA16(a,b,c) __builtin_amdgcn_mfma_f32_16x16x32_f16((a),(b),(c),0,0,0)

// global -> LDS direct DMA, 16B per lane. LDS dest is wave-uniform base + lane*16.
#define GLDS16(g,l) __builtin_amdgcn_global_load_lds( \
    (__attribute__((address_space(1))) void*)(g), \
    (__attribute__((address_space(3))) void*)(l), 16, 0, 0)

// ---------------- kernel 0a: x fp32 -> fp16 ----------------
__global__ __launch_bounds__(256) void k_cvt(const float* __restrict__ x,
                                             f16* __restrict__ xb) {
  const int n8 = MTOK * KD / 8;
  int i = blockIdx.x * blockDim.x + threadIdx.x;
  const int stride = gridDim.x * blockDim.x;
  for (; i < n8; i += stride) {
    f32x4 a = ((const f32x4*)x)[2 * i];
    f32x4 b = ((const f32x4*)x)[2 * i + 1];
    half8 h;
    h[0] = (f16)a[0]; h[1] = (f16)a[1]; h[2] = (f16)a[2]; h[3] = (f16)a[3];
    h[4] = (f16)b[0]; h[5] = (f16)b[1]; h[6] = (f16)b[2]; h[7] = (f16)b[3];
    ((half8*)xb)[i] = h;
  }
}

// ---------------- kernel 0b: W^T fp32 -> fp16 (B^T layout) ----------------
__global__ __launch_bounds__(256) void k_wt(const float* __restrict__ Wq,
                                            const float* __restrict__ Wk,
                                            const float* __restrict__ Wv,
                                            const float* __restrict__ Wo,
                                            f16* __restrict__ wt) {
  const int n = blockIdx.x;
  const float* W = (n < 512) ? Wq : (n < 1024) ? Wk : (n < 1536) ? Wv : Wo;
  const int c = n & 511;
  for (int k = threadIdx.x; k < 512; k += blockDim.x)
    wt[n * 512 + k] = (f16)W[k * 512 + c];
}

// ================= 256x256 8-phase GEMM mainloop (BK=64, K=512) =================
// A: [65536][512] f16 row-major. Bg: 256 rows (output channels) x 512 cols f16.
// acc[m][n]: wave (wm,wn) computes C rows arow0+wm*128+m*16+(frag), cols wn*64+n*16+(frag).
// SW=false: acc = mfma(a,b) -> D[token=g*4+r][chan=ln]
// SW=true : acc = mfma(b,a) -> D[chan=g*4+r][token=ln]
// LDS per buf: A: [ks2][256][32] (ks2 = k-half), B same. 2 bufs = 128 KiB.
// T2 swizzle: LDS[row][slot] holds global slot (slot ^ ((row>>1)&3)), slot=8-f16 chunk.

template<bool SW, int MB>
__device__ __forceinline__ void mfma16x(f32x4 (&acc)[8][4], half8 (&af)[4], half8 (&bf)[4]) {
#pragma unroll
  for (int i = 0; i < 4; ++i)
#pragma unroll
    for (int n = 0; n < 4; ++n) {
      if (SW) acc[MB + i][n] = MFMA16(bf[n], af[i], acc[MB + i][n]);
      else    acc[MB + i][n] = MFMA16(af[i], bf[n], acc[MB + i][n]);
    }
}

__device__ __forceinline__ void load4(const f16* base, half8 (&fr)[4]) {
#pragma unroll
  for (int n = 0; n < 4; ++n) fr[n] = *(const half8*)(base + n * 512);
}

#define BAR_MFMA_OPEN() __builtin_amdgcn_s_barrier(); \
  asm volatile("s_waitcnt lgkmcnt(0)" ::: "memory"); \
  __builtin_amdgcn_sched_barrier(0); \
  __builtin_amdgcn_s_setprio(1)
#define MFMA_CLOSE() __builtin_amdgcn_s_setprio(0); __builtin_amdgcn_s_barrier()
#define MFMA_CLOSE_GATE4() __builtin_amdgcn_s_setprio(0); \
  asm volatile("s_waitcnt vmcnt(4)" ::: "memory"); \
  __builtin_amdgcn_s_barrier()
#define MFMA_CLOSE_GATE0() __builtin_amdgcn_s_setprio(0); \
  asm volatile("s_waitcnt vmcnt(0)" ::: "memory"); \
  __builtin_amdgcn_s_barrier()

template<bool SW>
__device__ __forceinline__ void gemm256_main(
    const f16* __restrict__ Ag, const f16* __restrict__ Bg,
    int arow0, f16* lds, f32x4 (&acc)[8][4]) {
  const int tid = threadIdx.x;
  const int w = tid >> 6, lane = tid & 63;
  const int ln = lane & 15, g = lane >> 4;
  const int wm = w >> 2, wn = w & 3;
  const int slotx = ((g ^ ((ln >> 1) & 3)) << 3);

  f16* la = lds;           // [2][2][256][32]
  f16* lb = lds + 32768;

  // staging source offsets (f16 elements), per (ks2, r): row = r*128 + tid>>2,
  // source col-slot pre-swizzled so read-side XOR lands on correct data.
  const int gsrc = (((tid & 3) ^ ((tid >> 3) & 3)) << 3);
  int soA[4], soB[4];
#pragma unroll
  for (int ks2 = 0; ks2 < 2; ++ks2)
#pragma unroll
    for (int r = 0; r < 2; ++r) {
      soA[ks2 * 2 + r] = (arow0 + r * 128 + (tid >> 2)) * KD + ks2 * 32 + gsrc;
      soB[ks2 * 2 + r] = (r * 128 + (tid >> 2)) * KD + ks2 * 32 + gsrc;
    }
  const int ldst = w * 512;  // wave-uniform LDS chunk base (lane*16B added by HW)

#define STAGE_A(t, ks2, r) GLDS16((f16*)Ag + soA[(ks2)*2+(r)] + (t)*64, \
      la + ((t)&1)*16384 + (ks2)*8192 + (r)*4096 + ldst)
#define STAGE_B(t, ks2, r) GLDS16((f16*)Bg + soB[(ks2)*2+(r)] + (t)*64, \
      lb + ((t)&1)*16384 + (ks2)*8192 + (r)*4096 + ldst)

  const int raA = (wm * 128 + ln) * 32 + slotx;
  const int raB = (wn * 64 + ln) * 32 + slotx;

  // prologue: stage all of K-tile 0 into buf 0, full drain once
  STAGE_A(0, 0, 0); STAGE_A(0, 0, 1); STAGE_B(0, 0, 0); STAGE_B(0, 0, 1);
  STAGE_A(0, 1, 0); STAGE_A(0, 1, 1); STAGE_B(0, 1, 0); STAGE_B(0, 1, 1);
  asm volatile("s_waitcnt vmcnt(0)" ::: "memory");
  __builtin_amdgcn_s_barrier();

  half8 af[4], bf[4];

#pragma unroll 1
  for (int t = 0; t < 7; ++t) {
    const int cur = t & 1;
    const f16* lac = la + cur * 16384;
    const f16* lbc = lb + cur * 16384;
    // ph0: ks0, m0-3; stage A-ks0(t+1)
    load4(lbc + raB, bf);
    load4(lac + raA, af);
    STAGE_A(t + 1, 0, 0); STAGE_A(t + 1, 0, 1);
    BAR_MFMA_OPEN(); mfma16x<SW, 0>(acc, af, bf); MFMA_CLOSE();
    // ph1: ks0, m4-7; stage B-ks0(t+1); gate -> ks1(t) halves landed
    load4(lac + raA + 4 * 512, af);
    STAGE_B(t + 1, 0, 0); STAGE_B(t + 1, 0, 1);
    BAR_MFMA_OPEN(); mfma16x<SW, 4>(acc, af, bf); MFMA_CLOSE_GATE4();
    // ph2: ks1, m0-3; stage A-ks1(t+1)
    load4(lbc + 8192 + raB, bf);
    load4(lac + 8192 + raA, af);
    STAGE_A(t + 1, 1, 0); STAGE_A(t + 1, 1, 1);
    BAR_MFMA_OPEN(); mfma16x<SW, 0>(acc, af, bf); MFMA_CLOSE();
    // ph3: ks1, m4-7; stage B-ks1(t+1); gate -> ks0(t+1) halves landed
    load4(lac + 8192 + raA + 4 * 512, af);
    STAGE_B(t + 1, 1, 0); STAGE_B(t + 1, 1, 1);
    BAR_MFMA_OPEN(); mfma16x<SW, 4>(acc, af, bf); MFMA_CLOSE_GATE4();
  }
  // tail: K-tile 7 (buf 1), no staging; drain before ks1
  {
    const f16* lac = la + 16384;
    const f16* lbc = lb + 16384;
    load4(lbc + raB, bf);
    load4(lac + raA, af);
    BAR_MFMA_OPEN(); mfma16x<SW, 0>(acc, af, bf); MFMA_CLOSE();
    load4(lac + raA + 4 * 512, af);
    BAR_MFMA_OPEN(); mfma16x<SW, 4>(acc, af, bf); MFMA_CLOSE_GATE0();
    load4(lbc + 8192 + raB, bf);
    load4(lac + 8192 + raA, af);
    BAR_MFMA_OPEN(); mfma16x<SW, 0>(acc, af, bf); MFMA_CLOSE();
    load4(lac + 8192 + raA + 4 * 512, af);
    __builtin_amdgcn_s_barrier();
    asm volatile("s_waitcnt lgkmcnt(0)" ::: "memory");
    __builtin_amdgcn_sched_barrier(0);
    mfma16x<SW, 4>(acc, af, bf);
  }
#undef STAGE_A
#undef STAGE_B
}

// ---------------- kernel 1a: Q,K projection (swapped orientation) ----------------
__global__ __launch_bounds__(512, 2) void k_qk256(
    const f16* __restrict__ A, const f16* __restrict__ wt,
    const float* __restrict__ bq, const float* __restrict__ bk,
    f16* __restrict__ qb, f16* __restrict__ kb) {
  __shared__ f16 smem[65536];
  const int nwg8 = 1024 / 8;
  const int f = (blockIdx.x & 7) * nwg8 + (blockIdx.x >> 3);
  const int ntile = f & 3, mtile = f >> 2;
  const int arow0 = mtile * 256;
  const f16* Bg = wt + ntile * 256 * KD;

  f32x4 acc[8][4] = {};
  gemm256_main<true>(A, Bg, arow0, smem, acc);

  const int tid = threadIdx.x;
  const int w = tid >> 6, lane = tid & 63;
  const int ln = lane & 15, g = lane >> 4;
  const int wm = w >> 2, wn = w & 3;
  const int cslab = (ntile & 1) << 8;
  const float* bias = (ntile < 2) ? bq : bk;
  f16* dst = (ntile < 2) ? qb : kb;
#pragma unroll
  for (int n = 0; n < 4; ++n) {
    const int cg = cslab + wn * 64 + n * 16 + g * 4;
    const f32x4 b4 = *(const f32x4*)(bias + cg);
    const int h = cg >> 6, d = cg & 63;
#pragma unroll
    for (int m = 0; m < 8; ++m) {
      const int tk = arow0 + wm * 128 + m * 16 + ln;
      const int b = tk >> 7, tr = tk & 127;
      half4 o;
#pragma unroll
      for (int r = 0; r < 4; ++r) o[r] = (f16)(acc[m][n][r] + b4[r]);
      *(half4*)(dst + ((b * NH + h) * NQ + tr) * DH + d) = o;
    }
  }
}

// ---------------- kernel 1b: V projection (normal orientation, V^T out) ----------------
__global__ __launch_bounds__(512, 2) void k_v256(
    const f16* __restrict__ A, const f16* __restrict__ wt,
    const float* __restrict__ bv, f16* __restrict__ vb) {
  __shared__ f16 smem[65536];
  const int nwg8 = 512 / 8;
  const int f = (blockIdx.x & 7) * nwg8 + (blockIdx.x >> 3);
  const int ntile = f & 1, mtile = f >> 1;
  const int arow0 = mtile * 256;
  const f16* Bg = wt + (1024 + ntile * 256) * KD;

  f32x4 acc[8][4] = {};
  gemm256_main<false>(A, Bg, arow0, smem, acc);

  const int tid = threadIdx.x;
  const int w = tid >> 6, lane = tid & 63;
  const int ln = lane & 15, g = lane >> 4;
  const int wm = w >> 2, wn = w & 3;
#pragma unroll
  for (int n = 0; n < 4; ++n) {
    const int cg = ntile * 256 + wn * 64 + n * 16 + ln;
    const float bias = bv[cg];
    const int h = cg >> 6, d = cg & 63;
#pragma unroll
    for (int m = 0; m < 8; ++m) {
      const int t0 = arow0 + wm * 128 + m * 16 + g * 4;
      const int b = t0 >> 7, tr = t0 & 127;
      half4 o;
#pragma unroll
      for (int r = 0; r < 4; ++r) o[r] = (f16)(acc[m][n][r] + bias);
      *(half4*)(vb + ((b * NH + h) * DH + d) * NQ + tr) = o;
    }
  }
}

// ---------------- kernel 2: causal attention, one block per (b,h) ----------------
__global__ __launch_bounds__(256, 2) void k_attn(
    const f16* __restrict__ qbuf, const f16* __restrict__ kbuf,
    const f16* __restrict__ vbuf, f16* __restrict__ ao) {
  __shared__ f16 kl[128 * 72];
  __shared__ f16 vl[64 * 136];
  __shared__ f16 pl[128 * 136];
  const int bh = blockIdx.x;
  const f16* Qp = qbuf + bh * (NQ * DH);
  const f16* Kp = kbuf + bh * (NQ * DH);
  const f16* Vp = vbuf + bh * (DH * NQ);
  const int tid = threadIdx.x;
  const int w = tid >> 6, lane = tid & 63;
  const int ln = lane & 15, g = lane >> 4;

#pragma unroll
  for (int i = 0; i < 4; ++i) {
    const int e = i * 2048 + tid * 8;
    *(half8*)(kl + (e >> 6) * 72 + (e & 63)) = *(const half8*)(Kp + e);
  }
#pragma unroll
  for (int i = 0; i < 4; ++i) {
    const int e = i * 2048 + tid * 8;
    *(half8*)(vl + (e >> 7) * 136 + (e & 127)) = *(const half8*)(Vp + e);
  }
  half8 qf[2][2];
#pragma unroll
  for (int m = 0; m < 2; ++m)
#pragma unroll
    for (int ks = 0; ks < 2; ++ks)
      qf[m][ks] = *(const half8*)(Qp + (w * 32 + m * 16 + ln) * DH + ks * 32 + g * 8);
  __syncthreads();

  f32x4 s[2][8] = {};
#pragma unroll
  for (int ks = 0; ks < 2; ++ks)
#pragma unroll
    for (int n = 0; n < 8; ++n) {
      half8 kf = *(const half8*)(kl + (n * 16 + ln) * 72 + ks * 32 + g * 8);
      s[0][n] = MFMA16(qf[0][ks], kf, s[0][n]);
      s[1][n] = MFMA16(qf[1][ks], kf, s[1][n]);
    }

  float inv[2][4];
#pragma unroll
  for (int m = 0; m < 2; ++m) {
#pragma unroll
    for (int r = 0; r < 4; ++r) {
      const int q = w * 32 + m * 16 + g * 4 + r;
      float z[8];
      float rm = -1e30f;
#pragma unroll
      for (int n = 0; n < 8; ++n) {
        const int col = n * 16 + ln;
        float zz = s[m][n][r] * 0.125f + ((col > q) ? -12500.0f : 0.0f);
        z[n] = zz;
        rm = fmaxf(rm, zz);
      }
      rm = fmaxf(rm, __shfl_xor(rm, 1));
      rm = fmaxf(rm, __shfl_xor(rm, 2));
      rm = fmaxf(rm, __shfl_xor(rm, 4));
      rm = fmaxf(rm, __shfl_xor(rm, 8));
      float rs = 0.f;
#pragma unroll
      for (int n = 0; n < 8; ++n) {
        const float p = __expf(z[n] - rm);
        rs += p;
        pl[q * 136 + n * 16 + ln] = (f16)p;
      }
      rs += __shfl_xor(rs, 1);
      rs += __shfl_xor(rs, 2);
      rs += __shfl_xor(rs, 4);
      rs += __shfl_xor(rs, 8);
      inv[m][r] = 1.0f / rs;
    }
  }

  f32x4 o[2][4] = {};
#pragma unroll
  for (int ks = 0; ks < 4; ++ks) {
    half8 pf0 = *(const half8*)(pl + (w * 32 + ln) * 136 + ks * 32 + g * 8);
    half8 pf1 = *(const half8*)(pl + (w * 32 + 16 + ln) * 136 + ks * 32 + g * 8);
#pragma unroll
    for (int n = 0; n < 4; ++n) {
      half8 vf = *(const half8*)(vl + (n * 16 + ln) * 136 + ks * 32 + g * 8);
      o[0][n] = MFMA16(pf0, vf, o[0][n]);
      o[1][n] = MFMA16(pf1, vf, o[1][n]);
    }
  }

  const int b = bh >> 3, h = bh & 7;
  f16* dst = ao + (b * NQ) * CH + h * DH;
#pragma unroll
  for (int m = 0; m < 2; ++m)
#pragma unroll
    for (int n = 0; n < 4; ++n)
#pragma unroll
      for (int r = 0; r < 4; ++r) {
        const int q = w * 32 + m * 16 + g * 4 + r;
        dst[q * CH + n * 16 + ln] = (f16)(o[m][n][r] * inv[m][r]);
      }
}

// ---------------- kernel 3: output projection (swapped, fp32 out) ----------------
__global__ __launch_bounds__(512, 2) void k_out256(
    const f16* __restrict__ A, const f16* __restrict__ wt,
    const float* __restrict__ bo, float* __restrict__ out) {
  __shared__ f16 smem[65536];
  const int nwg8 = 512 / 8;
  const int f = (blockIdx.x & 7) * nwg8 + (blockIdx.x >> 3);
  const int ntile = f & 1, mtile = f >> 1;
  const int arow0 = mtile * 256;
  const f16* Bg = wt + (1536 + ntile * 256) * KD;

  f32x4 acc[8][4] = {};
  gemm256_main<true>(A, Bg, arow0, smem, acc);

  const int tid = threadIdx.x;
  const int w = tid >> 6, lane = tid & 63;
  const int ln = lane & 15, g = lane >> 4;
  const int wm = w >> 2, wn = w & 3;
#pragma unroll
  for (int n = 0; n < 4; ++n) {
    const int cg = ntile * 256 + wn * 64 + n * 16 + g * 4;
    const f32x4 b4 = *(const f32x4*)(bo + cg);
#pragma unroll
    for (int m = 0; m < 8; ++m) {
      const int tk = arow0 + wm * 128 + m * 16 + ln;
      f32x4 o = acc[m][n] + b4;
      *(f32x4*)(out + tk * CH + cg) = o;
    }
  }
}

extern "C" void kernel_launch(void* const* d_in, const int* in_sizes, int n_in,
                              void* d_out, int out_size, void* d_ws, size_t ws_size,
                              hipStream_t stream) {
  (void)in_sizes; (void)n_in; (void)out_size; (void)ws_size;
  const float* x  = (const float*)d_in[0];
  const float* Wq = (const float*)d_in[1];
  const float* bq = (const float*)d_in[2];
  const float* Wk = (const float*)d_in[3];
  const float* bk = (const float*)d_in[4];
  const float* Wv = (const float*)d_in[5];
  const float* bv = (const float*)d_in[6];
  const float* Wo = (const float*)d_in[7];
  const float* bo = (const float*)d_in[8];
  float* out = (float*)d_out;

  char* ws = (char*)d_ws;
  const size_t SZ = (size_t)MTOK * KD * sizeof(f16);  // 64 MB
  f16* xb = (f16*)(ws);
  f16* qb = (f16*)(ws + SZ);
  f16* kb = (f16*)(ws + 2 * SZ);
  f16* vb = (f16*)(ws + 3 * SZ);
  f16* wt = (f16*)(ws + 4 * SZ);
  f16* ao = xb;  // attn out aliases xb (xb dead after projections)

  k_cvt<<<2048, 256, 0, stream>>>(x, xb);
  k_wt<<<2048, 256, 0, stream>>>(Wq, Wk, Wv, Wo, wt);
  k_qk256<<<1024, 512, 0, stream>>>(xb, wt, bq, bk, qb, kb);
  k_v256<<<512, 512, 0, stream>>>(xb, wt, bv, vb);
  k_attn<<<4096, 256, 0, stream>>>(qb, kb, vb, ao);
  k_out256<<<512, 512, 0, stream>>>(ao, wt, bo, out);
}